// Round 1
// baseline (169.768 us; speedup 1.0000x reference)
//
#include <hip/hip_runtime.h>

// Problem constants (match reference: N=8192 queries, D=384, M=1024 docs)
#define N_Q  8192
#define DIM  384     // = 64*6
#define N_DOC 1024

// ---------------------------------------------------------------------------
// Kernel A: row-normalize emb_q -> nq.  One wave per row (384 = 64*6).
// ---------------------------------------------------------------------------
__global__ __launch_bounds__(256) void k_normalize(const float* __restrict__ emb,
                                                   float* __restrict__ nq) {
    int w    = (blockIdx.x * 256 + threadIdx.x) >> 6;   // row
    int lane = threadIdx.x & 63;
    const float* row = emb + (size_t)w * DIM;
    float v[6];
    float ss = 0.f;
#pragma unroll
    for (int r = 0; r < 6; ++r) { v[r] = row[lane + 64 * r]; ss += v[r] * v[r]; }
#pragma unroll
    for (int off = 32; off; off >>= 1) ss += __shfl_xor(ss, off);
    float inv = rsqrtf(ss);
    float* o = nq + (size_t)w * DIM;
#pragma unroll
    for (int r = 0; r < 6; ++r) o[lane + 64 * r] = v[r] * inv;
}

// ---------------------------------------------------------------------------
// Kernel B: per-doc weighted segment sum -> H[j,:] = (sum label*nq) / sum label
// One wave per doc id j. Deterministic: fixed chunk order + ordered ballot bits.
// ---------------------------------------------------------------------------
__global__ __launch_bounds__(64) void k_segsum(const float* __restrict__ nq,
                                               const float* __restrict__ label,
                                               const int*   __restrict__ ids,
                                               float* __restrict__ H) {
    int j    = blockIdx.x;
    int lane = threadIdx.x;
    float acc[6] = {0.f, 0.f, 0.f, 0.f, 0.f, 0.f};
    float den = 0.f;

    int idc = ids[lane];                       // prefetch chunk 0
    for (int base = 0; base < N_Q; base += 64) {
        int idn = (base + 64 < N_Q) ? ids[base + 64 + lane] : -1;
        unsigned long long mask = __ballot(idc == j);
        while (mask) {
            int b = __builtin_ctzll(mask);
            mask &= mask - 1;
            int q = base + b;
            float lab = label[q];
            const float* r = nq + (size_t)q * DIM;
#pragma unroll
            for (int t = 0; t < 6; ++t) acc[t] = fmaf(lab, r[lane + 64 * t], acc[t]);
            den += lab;
        }
        idc = idn;
    }
    float invd = (den > 0.f) ? (1.f / den) : 0.f;   // empty group -> 0 (never gathered)
    float* h = H + (size_t)j * DIM;
#pragma unroll
    for (int t = 0; t < 6; ++t) h[lane + 64 * t] = acc[t] * invd;
}

// ---------------------------------------------------------------------------
// Kernel C: T[i,j] = nq[i,:] . H[j,:]   (N_Q x N_DOC, K = DIM, fp32 tiled)
// 64x64 tile, 256 threads, each thread 4x4 micro-tile, BK=16.
// ---------------------------------------------------------------------------
__global__ __launch_bounds__(256) void k_gemm(const float* __restrict__ A,   // nq [N_Q][DIM]
                                              const float* __restrict__ B,   // H  [N_DOC][DIM]
                                              float* __restrict__ T) {       // [N_Q][N_DOC]
    __shared__ float As[16][64];   // [k][m]
    __shared__ float Bs[16][64];   // [k][n]
    int tid = threadIdx.x;
    int tx = tid & 15, ty = tid >> 4;
    int row0 = blockIdx.y << 6;
    int col0 = blockIdx.x << 6;

    // loader: each thread one float4 of A-tile and one of B-tile
    int lm = tid >> 2;            // 0..63 (tile row)
    int lk = (tid & 3) << 2;      // 0,4,8,12 (k offset)

    float acc[4][4] = {};
    for (int k0 = 0; k0 < DIM; k0 += 16) {
        float4 a4 = *(const float4*)(A + (size_t)(row0 + lm) * DIM + k0 + lk);
        float4 b4 = *(const float4*)(B + (size_t)(col0 + lm) * DIM + k0 + lk);
        As[lk + 0][lm] = a4.x; As[lk + 1][lm] = a4.y; As[lk + 2][lm] = a4.z; As[lk + 3][lm] = a4.w;
        Bs[lk + 0][lm] = b4.x; Bs[lk + 1][lm] = b4.y; Bs[lk + 2][lm] = b4.z; Bs[lk + 3][lm] = b4.w;
        __syncthreads();
#pragma unroll
        for (int kk = 0; kk < 16; ++kk) {
            float4 a = *(const float4*)&As[kk][ty << 2];
            float4 b = *(const float4*)&Bs[kk][tx << 2];
            float av[4] = {a.x, a.y, a.z, a.w};
            float bv[4] = {b.x, b.y, b.z, b.w};
#pragma unroll
            for (int i2 = 0; i2 < 4; ++i2)
#pragma unroll
                for (int j2 = 0; j2 < 4; ++j2)
                    acc[i2][j2] = fmaf(av[i2], bv[j2], acc[i2][j2]);
        }
        __syncthreads();
    }
#pragma unroll
    for (int i2 = 0; i2 < 4; ++i2) {
        float4 o = make_float4(acc[i2][0], acc[i2][1], acc[i2][2], acc[i2][3]);
        *(float4*)(T + (size_t)(row0 + (ty << 2) + i2) * N_DOC + col0 + (tx << 2)) = o;
    }
}

// ---------------------------------------------------------------------------
// Kernel D: out[i,q] = T[i, ids[q]].  One block per output row; T row staged
// in LDS (4 KB), int4 id loads, float4 stores (write-BW bound).
// ---------------------------------------------------------------------------
__global__ __launch_bounds__(256) void k_expand(const float* __restrict__ T,
                                                const int*   __restrict__ ids,
                                                float* __restrict__ out) {
    __shared__ float trow[N_DOC];
    int i = blockIdx.x;
    ((float4*)trow)[threadIdx.x] = ((const float4*)(T + (size_t)i * N_DOC))[threadIdx.x];
    __syncthreads();
    float* orow = out + (size_t)i * N_Q;
    const int4* id4 = (const int4*)ids;
#pragma unroll
    for (int it = 0; it < N_Q / 4 / 256; ++it) {   // 8 iterations
        int q4 = it * 256 + threadIdx.x;
        int4 id = id4[q4];
        float4 v = make_float4(trow[id.x], trow[id.y], trow[id.z], trow[id.w]);
        ((float4*)(orow))[q4] = v;
    }
}

// ---------------------------------------------------------------------------
extern "C" void kernel_launch(void* const* d_in, const int* in_sizes, int n_in,
                              void* d_out, int out_size, void* d_ws, size_t ws_size,
                              hipStream_t stream) {
    const float* emb   = (const float*)d_in[0];
    const float* label = (const float*)d_in[1];
    const int*   ids   = (const int*)d_in[2];
    float* out = (float*)d_out;

    // workspace layout (floats): nq[N_Q*DIM] | H[N_DOC*DIM] | T[N_Q*N_DOC]  ~45.5 MB
    float* nq = (float*)d_ws;
    float* H  = nq + (size_t)N_Q * DIM;
    float* T  = H  + (size_t)N_DOC * DIM;

    k_normalize<<<N_Q / 4, 256, 0, stream>>>(emb, nq);
    k_segsum<<<N_DOC, 64, 0, stream>>>(nq, label, ids, H);
    k_gemm<<<dim3(N_DOC / 64, N_Q / 64), 256, 0, stream>>>(nq, H, T);
    k_expand<<<N_Q, 256, 0, stream>>>(T, ids, out);
}

// Round 2
// 98.219 us; speedup vs baseline: 1.7285x; 1.7285x over previous
//
#include <hip/hip_runtime.h>

// Problem constants (reference: N=8192 queries, D=384, M=1024 docs)
#define N_Q   8192
#define DIM   384     // = 64*6 = 12 MFMA k-steps of 32
#define N_DOC 1024

typedef unsigned short ushort_t;
typedef __attribute__((ext_vector_type(8))) short bf16x8;
typedef __attribute__((ext_vector_type(4))) float f32x4;

__device__ __forceinline__ float bf2f(ushort_t u) {
    union { unsigned i; float f; } c; c.i = ((unsigned)u) << 16; return c.f;
}
__device__ __forceinline__ ushort_t f2bf(float f) {   // RNE
    union { float f; unsigned u; } c; c.f = f;
    unsigned r = c.u + 0x7FFF + ((c.u >> 16) & 1);
    return (ushort_t)(r >> 16);
}
__device__ __forceinline__ void gload_lds16(const void* g, void* l) {
    __builtin_amdgcn_global_load_lds((const __attribute__((address_space(1))) void*)g,
                                     (__attribute__((address_space(3))) void*)l, 16, 0, 0);
}

// ---------------------------------------------------------------------------
// Kernel A: row-normalize emb_q -> nq (bf16). One wave per row (384 = 64*6).
// ---------------------------------------------------------------------------
__global__ __launch_bounds__(256) void k_normalize(const float* __restrict__ emb,
                                                   ushort_t* __restrict__ nqb) {
    int w    = (blockIdx.x * 256 + threadIdx.x) >> 6;   // row
    int lane = threadIdx.x & 63;
    const float* row = emb + (size_t)w * DIM;
    float v[6];
    float ss = 0.f;
#pragma unroll
    for (int r = 0; r < 6; ++r) { v[r] = row[lane + 64 * r]; ss += v[r] * v[r]; }
#pragma unroll
    for (int off = 32; off; off >>= 1) ss += __shfl_xor(ss, off);
    float inv = rsqrtf(ss);
    ushort_t* o = nqb + (size_t)w * DIM;
#pragma unroll
    for (int r = 0; r < 6; ++r) o[lane + 64 * r] = f2bf(v[r] * inv);
}

// ---------------------------------------------------------------------------
// Kernel B: per-doc weighted segment sum -> H[j,:] (bf16), fp32 accum.
// One wave per doc id j. Deterministic (ordered ballot bits).
// ---------------------------------------------------------------------------
__global__ __launch_bounds__(64) void k_segsum(const ushort_t* __restrict__ nqb,
                                               const float* __restrict__ label,
                                               const int*   __restrict__ ids,
                                               ushort_t* __restrict__ Hb) {
    int j    = blockIdx.x;
    int lane = threadIdx.x;
    float acc[6] = {0.f, 0.f, 0.f, 0.f, 0.f, 0.f};
    float den = 0.f;

    int idc = ids[lane];
    for (int base = 0; base < N_Q; base += 64) {
        int idn = (base + 64 < N_Q) ? ids[base + 64 + lane] : -1;
        unsigned long long mask = __ballot(idc == j);
        while (mask) {
            int b = __builtin_ctzll(mask);
            mask &= mask - 1;
            int q = base + b;
            float lab = label[q];
            const ushort_t* r = nqb + (size_t)q * DIM;
#pragma unroll
            for (int t = 0; t < 6; ++t) acc[t] = fmaf(lab, bf2f(r[lane + 64 * t]), acc[t]);
            den += lab;
        }
        idc = idn;
    }
    float invd = (den > 0.f) ? (1.f / den) : 0.f;   // empty group -> 0 (never gathered)
    ushort_t* h = Hb + (size_t)j * DIM;
#pragma unroll
    for (int t = 0; t < 6; ++t) h[lane + 64 * t] = f2bf(acc[t] * invd);
}

// ---------------------------------------------------------------------------
// Kernel C: T[i,j] = nq[i,:] . H[j,:]  -- bf16 MFMA 16x16x32, fp32 accum.
// 128x128 tile, 4 waves (2x2), each wave 4x4 fragments (64x64). BK=64.
// global_load_lds width-16 staging, linear LDS dest + XOR-swizzled global
// source (granule gd holds global granule gd^(row&7)); fragment ds_read_b128
// applies the same XOR -> ~2-way banks (free).
// ---------------------------------------------------------------------------
#define BM 128
#define BN 128
#define BK 64

__global__ __launch_bounds__(256) void k_gemm(const ushort_t* __restrict__ A,  // nq bf16 [N_Q][DIM]
                                              const ushort_t* __restrict__ B,  // H  bf16 [N_DOC][DIM]
                                              float* __restrict__ T) {         // [N_Q][N_DOC]
    __shared__ ushort_t As[BM * BK];   // 16 KB, swizzled granules
    __shared__ ushort_t Bs[BN * BK];
    int tid  = threadIdx.x;
    int lane = tid & 63, wid = tid >> 6;
    int wr = wid >> 1, wc = wid & 1;             // 2x2 wave grid
    int row0 = blockIdx.y * BM, col0 = blockIdx.x * BN;
    int fr = lane & 15, kg = lane >> 4;

    f32x4 acc[4][4];
#pragma unroll
    for (int i = 0; i < 4; ++i)
#pragma unroll
        for (int j = 0; j < 4; ++j) acc[i][j] = (f32x4)0.f;

    for (int k0 = 0; k0 < DIM; k0 += BK) {
        // stage: 128 rows x 8 granules(16B) per matrix; 256 thr x 4 reps
#pragma unroll
        for (int r = 0; r < 4; ++r) {
            int flat = r * 256 + tid;
            int row = flat >> 3, gd = flat & 7;
            int gs = gd ^ (row & 7);                     // involutive source swizzle
            int wbase = (r * 256 + wid * 64) * 8;        // wave-uniform LDS elem base
            gload_lds16(A + (size_t)(row0 + row) * DIM + k0 + gs * 8, &As[wbase]);
            gload_lds16(B + (size_t)(col0 + row) * DIM + k0 + gs * 8, &Bs[wbase]);
        }
        __syncthreads();

#pragma unroll
        for (int ks = 0; ks < 2; ++ks) {                 // two k=32 steps per BK=64
            bf16x8 a[4], b[4];
#pragma unroll
            for (int mi = 0; mi < 4; ++mi) {
                int m = wr * 64 + mi * 16 + fr;
                a[mi] = *(const bf16x8*)&As[m * 64 + (((ks * 4 + kg) ^ (m & 7)) << 3)];
            }
#pragma unroll
            for (int ni = 0; ni < 4; ++ni) {
                int n = wc * 64 + ni * 16 + fr;
                b[ni] = *(const bf16x8*)&Bs[n * 64 + (((ks * 4 + kg) ^ (n & 7)) << 3)];
            }
#pragma unroll
            for (int mi = 0; mi < 4; ++mi)
#pragma unroll
                for (int ni = 0; ni < 4; ++ni)
                    acc[mi][ni] = __builtin_amdgcn_mfma_f32_16x16x32_bf16(a[mi], b[ni], acc[mi][ni], 0, 0, 0);
        }
        __syncthreads();
    }

    // C/D layout: col = lane&15, row = (lane>>4)*4 + reg   [m89]
#pragma unroll
    for (int mi = 0; mi < 4; ++mi)
#pragma unroll
        for (int ni = 0; ni < 4; ++ni)
#pragma unroll
            for (int r = 0; r < 4; ++r)
                T[(size_t)(row0 + wr * 64 + mi * 16 + kg * 4 + r) * N_DOC
                  + col0 + wc * 64 + ni * 16 + fr] = acc[mi][ni][r];
}

// ---------------------------------------------------------------------------
// Kernel D: out[i,q] = T[i, ids[q]].  One block per row; T row in LDS (4 KB),
// int4 id loads, float4 stores (write-BW bound).
// ---------------------------------------------------------------------------
__global__ __launch_bounds__(256) void k_expand(const float* __restrict__ T,
                                                const int*   __restrict__ ids,
                                                float* __restrict__ out) {
    __shared__ float trow[N_DOC];
    int i = blockIdx.x;
    ((float4*)trow)[threadIdx.x] = ((const float4*)(T + (size_t)i * N_DOC))[threadIdx.x];
    __syncthreads();
    float* orow = out + (size_t)i * N_Q;
    const int4* id4 = (const int4*)ids;
#pragma unroll
    for (int it = 0; it < N_Q / 4 / 256; ++it) {   // 8 iterations
        int q4 = it * 256 + threadIdx.x;
        int4 id = id4[q4];
        float4 v = make_float4(trow[id.x], trow[id.y], trow[id.z], trow[id.w]);
        ((float4*)(orow))[q4] = v;
    }
}

// ---------------------------------------------------------------------------
extern "C" void kernel_launch(void* const* d_in, const int* in_sizes, int n_in,
                              void* d_out, int out_size, void* d_ws, size_t ws_size,
                              hipStream_t stream) {
    const float* emb   = (const float*)d_in[0];
    const float* label = (const float*)d_in[1];
    const int*   ids   = (const int*)d_in[2];
    float* out = (float*)d_out;

    // workspace (bytes): nqb bf16 [N_Q*DIM] | Hb bf16 [N_DOC*DIM] | T f32 [N_Q*N_DOC]  ~40.6 MB
    ushort_t* nqb = (ushort_t*)d_ws;
    ushort_t* Hb  = nqb + (size_t)N_Q * DIM;
    float*    T   = (float*)(Hb + (size_t)N_DOC * DIM);

    k_normalize<<<N_Q / 4, 256, 0, stream>>>(emb, nqb);
    k_segsum<<<N_DOC, 64, 0, stream>>>(nqb, label, ids, Hb);
    k_gemm<<<dim3(N_DOC / BN, N_Q / BM), 256, 0, stream>>>(nqb, Hb, T);
    k_expand<<<N_Q, 256, 0, stream>>>(T, ids, out);
}

// Round 3
// 81.733 us; speedup vs baseline: 2.0771x; 1.2017x over previous
//
#include <hip/hip_runtime.h>

// Problem constants (reference: N=8192 queries, D=384, M=1024 docs)
#define N_Q   8192
#define DIM   384     // = 64*6 = 12 MFMA k-steps of 32
#define N_DOC 1024

typedef unsigned short ushort_t;
typedef __attribute__((ext_vector_type(8))) short bf16x8;
typedef __attribute__((ext_vector_type(4))) float f32x4;

__device__ __forceinline__ float bf2f(ushort_t u) {
    union { unsigned i; float f; } c; c.i = ((unsigned)u) << 16; return c.f;
}
__device__ __forceinline__ ushort_t f2bf(float f) {   // RNE
    union { float f; unsigned u; } c; c.f = f;
    unsigned r = c.u + 0x7FFF + ((c.u >> 16) & 1);
    return (ushort_t)(r >> 16);
}
__device__ __forceinline__ void gload_lds16(const void* g, void* l) {
    __builtin_amdgcn_global_load_lds((const __attribute__((address_space(1))) void*)g,
                                     (__attribute__((address_space(3))) void*)l, 16, 0, 0);
}

// ---------------------------------------------------------------------------
// Kernel A: row-normalize emb_q -> nq (bf16). One wave per row (384 = 64*6).
// ---------------------------------------------------------------------------
__global__ __launch_bounds__(256) void k_normalize(const float* __restrict__ emb,
                                                   ushort_t* __restrict__ nqb) {
    int w    = (blockIdx.x * 256 + threadIdx.x) >> 6;   // row
    int lane = threadIdx.x & 63;
    const float* row = emb + (size_t)w * DIM;
    float v[6];
    float ss = 0.f;
#pragma unroll
    for (int r = 0; r < 6; ++r) { v[r] = row[lane + 64 * r]; ss += v[r] * v[r]; }
#pragma unroll
    for (int off = 32; off; off >>= 1) ss += __shfl_xor(ss, off);
    float inv = rsqrtf(ss);
    ushort_t* o = nqb + (size_t)w * DIM;
#pragma unroll
    for (int r = 0; r < 6; ++r) o[lane + 64 * r] = f2bf(v[r] * inv);
}

// ---------------------------------------------------------------------------
// Kernel B: per-doc weighted segment sum -> H[j,:] (bf16), fp32 accum.
// 8 waves per doc; wave w scans queries [w*1024, (w+1)*1024); partials
// combined in LDS in fixed wave order (bit-deterministic).
// ---------------------------------------------------------------------------
#define SS_WAVES 8
__global__ __launch_bounds__(512) void k_segsum(const ushort_t* __restrict__ nqb,
                                                const float* __restrict__ label,
                                                const int*   __restrict__ ids,
                                                ushort_t* __restrict__ Hb) {
    __shared__ float pacc[SS_WAVES][DIM];
    __shared__ float pden[SS_WAVES];
    int j    = blockIdx.x;
    int lane = threadIdx.x & 63;
    int w    = threadIdx.x >> 6;
    const int span = N_Q / SS_WAVES;          // 1024
    int q0 = w * span;

    float acc[6] = {0.f, 0.f, 0.f, 0.f, 0.f, 0.f};
    float den = 0.f;

    int idc = ids[q0 + lane];
    for (int base = q0; base < q0 + span; base += 64) {
        int nb = base + 64;
        int idn = (nb < q0 + span) ? ids[nb + lane] : -1;
        unsigned long long mask = __ballot(idc == j);
        while (mask) {
            int b = __builtin_ctzll(mask);
            mask &= mask - 1;
            int q = base + b;
            float lab = label[q];
            const ushort_t* r = nqb + (size_t)q * DIM;
#pragma unroll
            for (int t = 0; t < 6; ++t) acc[t] = fmaf(lab, bf2f(r[lane + 64 * t]), acc[t]);
            den += lab;
        }
        idc = idn;
    }
#pragma unroll
    for (int t = 0; t < 6; ++t) pacc[w][lane + 64 * t] = acc[t];
    if (lane == 0) pden[w] = den;
    __syncthreads();

    int d = threadIdx.x;
    if (d < DIM) {
        float s = 0.f, dn = 0.f;
#pragma unroll
        for (int ww = 0; ww < SS_WAVES; ++ww) { s += pacc[ww][d]; dn += pden[ww]; }
        float invd = (dn > 0.f) ? (1.f / dn) : 0.f;   // empty group -> 0 (never gathered)
        Hb[(size_t)j * DIM + d] = f2bf(s * invd);
    }
}

// ---------------------------------------------------------------------------
// Kernel C: T[i,j] = nq[i,:] . H[j,:]  -- bf16 MFMA 16x16x32, fp32 accum.
// 128x128 tile, 4 waves (2x2), each wave 4x4 fragments (64x64). BK=64.
// global_load_lds width-16 staging, linear LDS dest + XOR-swizzled global
// source; fragment ds_read_b128 applies the same XOR -> ~2-way banks.
// ---------------------------------------------------------------------------
#define BM 128
#define BN 128
#define BK 64

__global__ __launch_bounds__(256) void k_gemm(const ushort_t* __restrict__ A,  // nq bf16 [N_Q][DIM]
                                              const ushort_t* __restrict__ B,  // H  bf16 [N_DOC][DIM]
                                              float* __restrict__ T) {         // [N_Q][N_DOC]
    __shared__ ushort_t As[BM * BK];   // 16 KB, swizzled granules
    __shared__ ushort_t Bs[BN * BK];
    int tid  = threadIdx.x;
    int lane = tid & 63, wid = tid >> 6;
    int wr = wid >> 1, wc = wid & 1;             // 2x2 wave grid
    int row0 = blockIdx.y * BM, col0 = blockIdx.x * BN;
    int fr = lane & 15, kg = lane >> 4;

    f32x4 acc[4][4];
#pragma unroll
    for (int i = 0; i < 4; ++i)
#pragma unroll
        for (int j = 0; j < 4; ++j) acc[i][j] = (f32x4)0.f;

    for (int k0 = 0; k0 < DIM; k0 += BK) {
#pragma unroll
        for (int r = 0; r < 4; ++r) {
            int flat = r * 256 + tid;
            int row = flat >> 3, gd = flat & 7;
            int gs = gd ^ (row & 7);                     // involutive source swizzle
            int wbase = (r * 256 + wid * 64) * 8;        // wave-uniform LDS elem base
            gload_lds16(A + (size_t)(row0 + row) * DIM + k0 + gs * 8, &As[wbase]);
            gload_lds16(B + (size_t)(col0 + row) * DIM + k0 + gs * 8, &Bs[wbase]);
        }
        __syncthreads();

#pragma unroll
        for (int ks = 0; ks < 2; ++ks) {                 // two k=32 steps per BK=64
            bf16x8 a[4], b[4];
#pragma unroll
            for (int mi = 0; mi < 4; ++mi) {
                int m = wr * 64 + mi * 16 + fr;
                a[mi] = *(const bf16x8*)&As[m * 64 + (((ks * 4 + kg) ^ (m & 7)) << 3)];
            }
#pragma unroll
            for (int ni = 0; ni < 4; ++ni) {
                int n = wc * 64 + ni * 16 + fr;
                b[ni] = *(const bf16x8*)&Bs[n * 64 + (((ks * 4 + kg) ^ (n & 7)) << 3)];
            }
#pragma unroll
            for (int mi = 0; mi < 4; ++mi)
#pragma unroll
                for (int ni = 0; ni < 4; ++ni)
                    acc[mi][ni] = __builtin_amdgcn_mfma_f32_16x16x32_bf16(a[mi], b[ni], acc[mi][ni], 0, 0, 0);
        }
        __syncthreads();
    }

    // C/D layout: col = lane&15, row = (lane>>4)*4 + reg   [m89]
#pragma unroll
    for (int mi = 0; mi < 4; ++mi)
#pragma unroll
        for (int ni = 0; ni < 4; ++ni)
#pragma unroll
            for (int r = 0; r < 4; ++r)
                T[(size_t)(row0 + wr * 64 + mi * 16 + kg * 4 + r) * N_DOC
                  + col0 + wc * 64 + ni * 16 + fr] = acc[mi][ni][r];
}

// ---------------------------------------------------------------------------
// Kernel D: out[i,q] = T[i, ids[q]].  Two rows per block; T rows staged in
// LDS (8 KB); id4 loaded once and reused for both rows (write-BW bound).
// ---------------------------------------------------------------------------
__global__ __launch_bounds__(256) void k_expand(const float* __restrict__ T,
                                                const int*   __restrict__ ids,
                                                float* __restrict__ out) {
    __shared__ float trow[2][N_DOC];
    int i0 = blockIdx.x * 2;
    const float4* Tv = (const float4*)(T + (size_t)i0 * N_DOC);
    ((float4*)trow[0])[threadIdx.x]       = Tv[threadIdx.x];
    ((float4*)trow[0])[threadIdx.x + 256] = Tv[threadIdx.x + 256];
    __syncthreads();
    float* o0 = out + (size_t)i0 * N_Q;
    float* o1 = o0 + N_Q;
    const int4* id4 = (const int4*)ids;
#pragma unroll
    for (int it = 0; it < N_Q / 4 / 256; ++it) {   // 8 iterations
        int q4 = it * 256 + threadIdx.x;
        int4 id = id4[q4];
        ((float4*)o0)[q4] = make_float4(trow[0][id.x], trow[0][id.y], trow[0][id.z], trow[0][id.w]);
        ((float4*)o1)[q4] = make_float4(trow[1][id.x], trow[1][id.y], trow[1][id.z], trow[1][id.w]);
    }
}

// ---------------------------------------------------------------------------
extern "C" void kernel_launch(void* const* d_in, const int* in_sizes, int n_in,
                              void* d_out, int out_size, void* d_ws, size_t ws_size,
                              hipStream_t stream) {
    const float* emb   = (const float*)d_in[0];
    const float* label = (const float*)d_in[1];
    const int*   ids   = (const int*)d_in[2];
    float* out = (float*)d_out;

    // workspace: nqb bf16 [N_Q*DIM] | Hb bf16 [N_DOC*DIM] | T f32 [N_Q*N_DOC]
    ushort_t* nqb = (ushort_t*)d_ws;
    ushort_t* Hb  = nqb + (size_t)N_Q * DIM;
    float*    T   = (float*)(Hb + (size_t)N_DOC * DIM);

    k_normalize<<<N_Q / 4, 256, 0, stream>>>(emb, nqb);
    k_segsum<<<N_DOC, 512, 0, stream>>>(nqb, label, ids, Hb);
    k_gemm<<<dim3(N_DOC / BN, N_Q / BM), 256, 0, stream>>>(nqb, Hb, T);
    k_expand<<<N_Q / 2, 256, 0, stream>>>(T, ids, out);
}